// Round 9
// baseline (43724.393 us; speedup 1.0000x reference)
//
#include <hip/hip_runtime.h>
#include <stdint.h>

// AutoRegressiveModel: 47 outer x 512 inner sequential LSTM steps (mid=256),
// Bernoulli sampling bit-matches JAX threefry2x32 (partitionable mode).
//
// R11: wave-autonomous steps. Ledger R2-R10: exchange medium (L3->L2) null,
// barrier drain ~-1ms, obs chain null, poll depth null, clock forcing
// negative. Remaining theory: the step floor is the NUMBER of serial hops
// (poll -> barrier1 -> matvec -> barrier2 -> wave0-only epilogue -> store)
// plus cross-wave alignment. R11 removes ALL intra-block sync:
//   wave w of block b owns rows jglob in [16b+4w, 16b+4w+4);
//   lane = gate*16 + jj*4 + q (q = column quarter).
//   - lane polls its 4 tagged h-words from h_hist, ds_writes into a
//     WAVE-PRIVATE padded hstage (72-float quarter stride: read banks
//     {0,8,16,24} disjoint -> conflict-free broadcast; R4-verified fix),
//     lgkmcnt(0) only -- no s_barrier anywhere in the loop.
//   - matvec 64 MACs/lane (same quarter association as R5) -> 2x shfl_xor
//     quarter reduce -> 3x shfl gate gather -> activations -> c/h update:
//     all intra-wave, FP order expression-identical to R5.
//   - producer's 4 h-stores = one contiguous 32B store instruction; own
//     words short-circuit via wave-private LDS (skip lane 4b+w).
//   - obs-ring prefetch replicated per wave (off-path).
//   - election/heater/memset machinery dropped (clean 17-block launch).
// 64 independent wave-pipelines, data-tag synchronized (max skew 1 step,
// ring depth 512 -> no WAR; stale cross-dispatch tags can never match).

#define MID      256
#define NOUT     48
#define NSEQ     512
#define NOUTER   47
#define NSTEP    (NOUTER * NSEQ)   // 24064
#define NBLK     16
#define MAGIC_V  0x1234ABCDu
#define LOG2E    1.4426950408889634f
#define QSTRIDE  72               // padded quarter stride (floats), 72%32=8

typedef __attribute__((ext_vector_type(4))) float f32x4;

#define LD_REL(p) __hip_atomic_load((p), __ATOMIC_RELAXED, __HIP_MEMORY_SCOPE_AGENT)

// wave-internal LDS fence: order ds_write -> ds_read without a barrier.
#define LGKM_FENCE() do {                                   \
    asm volatile("s_waitcnt lgkmcnt(0)" ::: "memory");      \
    __builtin_amdgcn_sched_barrier(0);                      \
  } while (0)

__device__ __forceinline__ uint32_t rotl32(uint32_t x, int d) {
  return (x << d) | (x >> (32 - d));
}

// Exact JAX threefry2x32 (20 rounds).
__device__ __forceinline__ void threefry2x32(uint32_t k0, uint32_t k1,
                                             uint32_t x0, uint32_t x1,
                                             uint32_t& o0, uint32_t& o1) {
  uint32_t ks2 = k0 ^ k1 ^ 0x1BD11BDAu;
  uint32_t v0 = x0 + k0, v1 = x1 + k1;
#define TF_R(r) { v0 += v1; v1 = rotl32(v1, r); v1 ^= v0; }
  TF_R(13) TF_R(15) TF_R(26) TF_R(6)
  v0 += k1;  v1 += ks2 + 1u;
  TF_R(17) TF_R(29) TF_R(16) TF_R(24)
  v0 += ks2; v1 += k0 + 2u;
  TF_R(13) TF_R(15) TF_R(26) TF_R(6)
  v0 += k0;  v1 += k1 + 3u;
  TF_R(17) TF_R(29) TF_R(16) TF_R(24)
  v0 += k1;  v1 += ks2 + 4u;
  TF_R(13) TF_R(15) TF_R(26) TF_R(6)
  v0 += ks2; v1 += k0 + 5u;
#undef TF_R
  o0 = v0; o1 = v1;
}

// Accurate sigmoid for the sampler (off critical path).
__device__ __forceinline__ float sigf(float x) { return 1.0f / (1.0f + expf(-x)); }

__device__ __forceinline__ uint64_t packht(float h, uint32_t tag) {
  return ((uint64_t)tag << 32) | (uint64_t)__float_as_uint(h);
}

__global__ __launch_bounds__(256, 1)
void arlstm_kernel(const float* __restrict__ W_ih, const float* __restrict__ W_hh,
                   const float* __restrict__ b_ih, const float* __restrict__ b_hh,
                   const float* __restrict__ W_out, const float* __restrict__ b_out,
                   float* __restrict__ out, uint64_t* __restrict__ ws) {
  // ws layout (u64 units):
  uint64_t* h_hist = ws;                                  // [512][256] tagged
  float*    obsbuf = (float*)(ws + 512 * 256);            // [2][512][2]
  uint32_t* p_prog = (uint32_t*)(obsbuf + 2 * 512 * 2);   // [4] sampler progress
  uint32_t* magic  = p_prog + 16;
  uint64_t* ob64   = (uint64_t*)obsbuf;                   // pair view (8B aligned)

  const int tid = threadIdx.x;
  const int blk = blockIdx.x;

  __shared__ __align__(16) float hst[4][2][4 * QSTRIDE];  // wave-private, padded
  __shared__ float ring[4][2][16][2];                     // per-wave obs ring
  __shared__ float lp_acc[512];
  __shared__ float ent_acc[512];
  __shared__ float red[256];

  if (blk == NBLK) {
    // ----------------------- init + sampler block -----------------------
    // h_hist slot 0 holds h_0 = 0 with tag 0.
    __hip_atomic_store(&h_hist[tid], 0ull, __ATOMIC_RELAXED, __HIP_MEMORY_SCOPE_AGENT);
    if (tid < 16)
      __hip_atomic_store(&p_prog[tid], 0u, __ATOMIC_RELAXED, __HIP_MEMORY_SCOPE_AGENT);
    out[(tid)       * NOUT] = 0.0f;   // samples column 0 = zeros
    out[(tid + 256) * NOUT] = 0.0f;
    lp_acc[tid] = 0.0f;  lp_acc[tid + 256] = 0.0f;
    ent_acc[tid] = 0.0f; ent_acc[tid + 256] = 0.0f;
    __threadfence();
    __syncthreads();
    if (tid == 0)
      __hip_atomic_store(magic, MAGIC_V, __ATOMIC_RELEASE, __HIP_MEMORY_SCOPE_AGENT);

    const int w    = tid >> 6;   // wave 0..3 handles steps s with (s-1)&3 == w
    const int lane = tid & 63;
    const float wo0 = W_out[lane * 4 + 0], wo1 = W_out[lane * 4 + 1];
    const float wo2 = W_out[lane * 4 + 2], wo3 = W_out[lane * 4 + 3];
    const float bo = b_out[0];

    for (int s = w + 1; s <= NSTEP; s += 4) {
      const int k = (s - 1) >> 9;
      const int t = (s - 1) & 511;
      uint64_t* src = h_hist + (uint64_t)(s & 511) * 256 + lane * 4;
      uint64_t v0, v1, v2, v3;
      for (;;) {
        v0 = LD_REL(src + 0);
        v1 = LD_REL(src + 1);
        v2 = LD_REL(src + 2);
        v3 = LD_REL(src + 3);
        int ok = ((uint32_t)(v0 >> 32) == (uint32_t)s) &
                 ((uint32_t)(v1 >> 32) == (uint32_t)s) &
                 ((uint32_t)(v2 >> 32) == (uint32_t)s) &
                 ((uint32_t)(v3 >> 32) == (uint32_t)s);
        if (__all(ok)) break;
      }
      float zp = fmaf(__uint_as_float((uint32_t)v0), wo0,
                 fmaf(__uint_as_float((uint32_t)v1), wo1,
                 fmaf(__uint_as_float((uint32_t)v2), wo2,
                      __uint_as_float((uint32_t)v3) * wo3)));
      zp += __shfl_xor(zp, 1);
      zp += __shfl_xor(zp, 2);
      zp += __shfl_xor(zp, 4);
      zp += __shfl_xor(zp, 8);
      zp += __shfl_xor(zp, 16);
      zp += __shfl_xor(zp, 32);
      const float p = sigf(zp + bo);

      // JAX partitionable threefry: key_k = tf((0,42),(0,k)); bits = xor of
      // tf(key_k,(0,t)); u = bitcast((bits>>9)|0x3f800000)-1; sample = u < p.
      uint32_t ka, kb, c1, c2;
      threefry2x32(0u, 42u, 0u, (uint32_t)k, ka, kb);
      threefry2x32(ka, kb, 0u, (uint32_t)t, c1, c2);
      const uint32_t bits = c1 ^ c2;
      const float u = __uint_as_float((bits >> 9) | 0x3f800000u) - 1.0f;
      const float smp = (u < p) ? 1.0f : 0.0f;

      if (lane == 0) {
        uint32_t* ob = (uint32_t*)(obsbuf + ((k + 1) & 1) * (512 * 2) + t * 2);
        __hip_atomic_store(&ob[0], __float_as_uint(smp), __ATOMIC_RELAXED, __HIP_MEMORY_SCOPE_AGENT);
        __hip_atomic_store(&ob[1], __float_as_uint(p),   __ATOMIC_RELAXED, __HIP_MEMORY_SCOPE_AGENT);
        __hip_atomic_store(&p_prog[w], (uint32_t)s, __ATOMIC_RELEASE, __HIP_MEMORY_SCOPE_AGENT);
        out[t * NOUT + (k + 1)] = smp;
        const float lg = logf(p), lg1 = log1pf(-p);
        lp_acc[t]  += (smp > 0.5f) ? lg : lg1;
        ent_acc[t] -= (p * lg + (1.0f - p) * lg1);
      }
    }
    __syncthreads();
    // final outputs: logprobs (centered), entropies (mean over 47)
    red[tid] = lp_acc[tid] + lp_acc[tid + 256];
    __syncthreads();
    for (int off = 128; off > 0; off >>= 1) {
      if (tid < off) red[tid] += red[tid + off];
      __syncthreads();
    }
    const float mean = red[0] * (1.0f / 512.0f);
    out[24576 + tid]        = lp_acc[tid]        - mean;
    out[24576 + 256 + tid]  = lp_acc[tid + 256]  - mean;
    out[25088 + tid]        = ent_acc[tid]       * (1.0f / 47.0f);
    out[25088 + 256 + tid]  = ent_acc[tid + 256] * (1.0f / 47.0f);
  } else {
    // ---------------- LSTM worker: 4 autonomous waves ----------------
    // lane = gate*16 + jj*4 + q ; wave w owns jglob in [16b+4w, 16b+4w+4).
    const int w    = tid >> 6;
    const int lane = tid & 63;
    const int q    = lane & 3;            // column quarter
    const int jj   = (lane >> 2) & 3;     // local j within wave
    const int g    = lane >> 4;           // gate 0..3 (i,f,g,o)
    const int jglob = blk * 16 + 4 * w + jj;
    const int row   = g * 256 + blk * 16 + 4 * w + jj;   // W row (1024x256)
    const int Lown  = 4 * blk + w;        // lane whose 4-word group is own

    // W_hh slice in true VGPRs (asm pin prevents rematerialized reloads).
    f32x4 w4[16];
    const f32x4* wsrc = (const f32x4*)(W_hh + row * 256 + q * 64);
#pragma unroll
    for (int i = 0; i < 16; ++i) w4[i] = wsrc[i];
#pragma unroll
    for (int i = 0; i < 16; ++i) asm volatile("" : "+v"(w4[i]));

    // Per-lane row constants (every lane owns one gate row now).
    const float bb  = b_ih[row] + b_hh[row];
    const float wx0 = W_ih[row * 2 + 0];
    const float wx1 = W_ih[row * 2 + 1];
    const float mconst = (g == 2) ? (-2.0f * LOG2E) : (-LOG2E);  // act = ml*sig(sc*x)+ad
    const float ml     = (g == 2) ? 2.0f : 1.0f;
    const float ad     = (g == 2) ? -1.0f : 0.0f;

    // init: h-buffer for s=1 (all zeros), obs ring batch 0 zeros
    {
      f32x4 z = {0.f, 0.f, 0.f, 0.f};
      *(f32x4*)&hst[w][1][(lane >> 4) * QSTRIDE + (lane & 15) * 4] = z;
      *(f32x4*)&hst[w][0][(lane >> 4) * QSTRIDE + (lane & 15) * 4] = z;
      if (lane < 16) {
        ring[w][0][lane][0] = 0.f; ring[w][0][lane][1] = 0.f;
        ring[w][1][lane][0] = 0.f; ring[w][1][lane][1] = 0.f;
      }
    }

    if (tid == 0) {
      while (__hip_atomic_load(magic, __ATOMIC_ACQUIRE, __HIP_MEMORY_SCOPE_AGENT) != MAGIC_V) {}
    }
    __syncthreads();   // the ONLY block-wide barrier (startup)

    float c_st = 0.0f;                    // cell state (gate-0 lanes)

    // obs prefetch pipeline state (per wave, lanes 0..15)
    int      pf_tgt = 0, pf_need = 0;
    uint32_t pf_ppv = 0;
    uint64_t pf_ov  = 0;

    for (int s = 1; s <= NSTEP; ++s) {
      const int ph = (s - 1) & 15;

      // ---- obs prefetch: 3-phase, once per 16 steps (every wave) ----
      if (ph == 0) {
        pf_tgt  = s + 16 + lane;
        pf_need = 0;
        if (lane < 16 && pf_tgt > NSEQ && pf_tgt <= NSTEP) {
          pf_need = pf_tgt - NSEQ;                 // sampler step required
          pf_ppv  = LD_REL(&p_prog[(pf_need - 1) & 3]);
        }
      } else if (ph == 1) {
        bool ok = (pf_need == 0) || (pf_ppv >= (uint32_t)pf_need);
        while (!__all(ok)) {                       // essentially never taken
          if (!ok) pf_ppv = LD_REL(&p_prog[(pf_need - 1) & 3]);
          ok = (pf_need == 0) || (pf_ppv >= (uint32_t)pf_need);
        }
        pf_ov = 0;
        if (lane < 16 && pf_need != 0) {           // flag seen -> data safe
          const int kk = (pf_tgt - 1) >> 9;
          const int tt = (pf_tgt - 1) & 511;
          pf_ov = LD_REL(ob64 + (kk & 1) * 512 + tt);
        }
      } else if (ph == 2) {
        if (lane < 16) {
          const int par = (((s - 3) >> 4) + 1) & 1;   // parity of batch b+1
          ring[w][par][lane][0] = __uint_as_float((uint32_t)pf_ov);
          ring[w][par][lane][1] = __uint_as_float((uint32_t)(pf_ov >> 32));
        }
      }

      // ---- poll own 4-word group of h_{s-1}; stage into wave-private LDS ----
      // (own group arrives via producer's LDS short-circuit; h_0 is zeros)
      if (s > 1) {
        uint64_t* src = h_hist + (uint64_t)((s - 1) & 511) * 256 + 4 * lane;
        const uint32_t want = (uint32_t)(s - 1);
        uint64_t v0, v1, v2, v3;
        for (;;) {
          v0 = LD_REL(src + 0);
          v1 = LD_REL(src + 1);
          v2 = LD_REL(src + 2);
          v3 = LD_REL(src + 3);
          int ok = (lane == Lown) |
                   (((uint32_t)(v0 >> 32) == want) &
                    ((uint32_t)(v1 >> 32) == want) &
                    ((uint32_t)(v2 >> 32) == want) &
                    ((uint32_t)(v3 >> 32) == want));
          if (__all(ok)) break;
        }
        if (lane != Lown) {
          f32x4 hw;
          hw[0] = __uint_as_float((uint32_t)v0);
          hw[1] = __uint_as_float((uint32_t)v1);
          hw[2] = __uint_as_float((uint32_t)v2);
          hw[3] = __uint_as_float((uint32_t)v3);
          *(f32x4*)&hst[w][s & 1][(lane >> 4) * QSTRIDE + (lane & 15) * 4] = hw;
        }
      }
      LGKM_FENCE();   // wave-internal ds_write -> ds_read ordering; NO barrier

      // ---- matvec: 64 MACs over column quarter q (broadcast per q-group) ----
      float a0 = 0.f, a1 = 0.f, a2 = 0.f, a3 = 0.f;
      const f32x4* hs4 = (const f32x4*)&hst[w][s & 1][q * QSTRIDE];
#pragma unroll
      for (int i = 0; i < 16; ++i) {
        const f32x4 hv = hs4[i];
        a0 = fmaf(w4[i][0], hv[0], a0);
        a1 = fmaf(w4[i][1], hv[1], a1);
        a2 = fmaf(w4[i][2], hv[2], a2);
        a3 = fmaf(w4[i][3], hv[3], a3);
      }
      float gp = (a0 + a1) + (a2 + a3);
      gp += __shfl_xor(gp, 1);            // reduce over column quarters (q)
      gp += __shfl_xor(gp, 2);            // -> ((q0+q1)+(q2+q3)), R5 order

      const float sx = ring[w][((s - 1) >> 4) & 1][ph][0];
      const float px = ring[w][((s - 1) >> 4) & 1][ph][1];
      const float base = wx0 * sx + wx1 * px + bb;
      const float gv = gp + base;

      // act = sig(gv) for gates i,f,o; tanh(gv) = 2*sig(2gv)-1 for gate g.
      const float e   = __builtin_amdgcn_exp2f(gv * mconst);
      const float y   = __builtin_amdgcn_rcpf(1.0f + e);
      const float act = __builtin_fmaf(ml, y, ad);

      const float a_f = __shfl(act, (lane & 15) + 16, 64);
      const float a_g = __shfl(act, (lane & 15) + 32, 64);
      const float a_o = __shfl(act, (lane & 15) + 48, 64);

      if (g == 0) {                       // gate-0 lanes: c/h update (x4 redundant)
        const float t1 = a_f * c_st;
        const float t2 = act * a_g;       // act = sig(i)
        c_st = t1 + t2;
        const float ec = __builtin_amdgcn_exp2f(c_st * (-2.0f * LOG2E));
        const float yc = __builtin_amdgcn_rcpf(1.0f + ec);
        const float th = __builtin_fmaf(2.0f, yc, -1.0f);
        const float hnew = a_o * th;
        if (q == 0) {                     // one producer lane per jglob
          // own-wave short-circuit for step s+1 (wave-private buffer)
          hst[w][(s + 1) & 1][(jglob >> 6) * QSTRIDE + (jglob & 63)] = hnew;
          // 4 lanes (jj=0..3) -> one contiguous 32B tagged store
          __hip_atomic_store(&h_hist[(uint64_t)(s & 511) * 256 + jglob],
                             packht(hnew, (uint32_t)s),
                             __ATOMIC_RELAXED, __HIP_MEMORY_SCOPE_AGENT);
        }
      }
    }
  }
}

extern "C" void kernel_launch(void* const* d_in, const int* in_sizes, int n_in,
                              void* d_out, int out_size, void* d_ws, size_t ws_size,
                              hipStream_t stream) {
  const float* W_ih  = (const float*)d_in[0];
  const float* W_hh  = (const float*)d_in[1];
  const float* b_ih  = (const float*)d_in[2];
  const float* b_hh  = (const float*)d_in[3];
  const float* W_out = (const float*)d_in[4];
  const float* b_out = (const float*)d_in[5];
  float* out = (float*)d_out;
  uint64_t* ws = (uint64_t*)d_ws;

  arlstm_kernel<<<dim3(NBLK + 1), dim3(256), 0, stream>>>(
      W_ih, W_hh, b_ih, b_hh, W_out, b_out, out, ws);
}

// Round 10
// 31847.784 us; speedup vs baseline: 1.3729x; 1.3729x over previous
//
#include <hip/hip_runtime.h>
#include <stdint.h>

// AutoRegressiveModel: 47 outer x 512 inner sequential LSTM steps (mid=256),
// Bernoulli sampling bit-matches JAX threefry2x32 (partitionable mode).
//
// Persistent dataflow kernel: 17 blocks x 256 threads.
//   blocks 0..15 : LSTM workers. Block b owns h indices [16b,16b+16).
//                  W_hh slice (64 rows x 256 cols) in VGPRs (64 fp32/thread).
//   block 16     : init + sampler (p = sigmoid(h.W_out+b), threefry RNG,
//                  logprob/entropy accumulation, obs feedback).
//
// FINAL (R12): revert to the verified-best variant (31.76 ms). The R3-R11
// exploration falsified every candidate mechanism for the ~1.32us/step
// floor: lane remap / single barrier (-6ms), obs-chain prefetch (null),
// LDS-only barriers (null in bundle), exchange medium L3->L2 via same-XCD
// sc0 (engaged, FETCH 207->71MB, null), poll depth (null), DPM clock
// forcing (negative), wave-autonomous no-barrier steps (negative: the
// all-to-all h dependence IS the alignment cost). Floor arithmetic:
// 24064 sequential steps x (store->fabric visibility->discovery + sync +
// matvec) ~ 1.3us at the SMU-chosen clock = ~31.8ms = this kernel, within
// 2%. Latency-bound by inter-CU fabric round-trip; no CDNA4 mechanism
// (no remote-LDS push, no controllable clock, VGPR file < W_hh) remains.

#define MID      256
#define NOUT     48
#define NSEQ     512
#define NOUTER   47
#define NSTEP    (NOUTER * NSEQ)   // 24064
#define NBLK     16
#define MAGIC_V  0x1234ABCDu
#define LOG2E    1.4426950408889634f

__device__ __forceinline__ uint32_t rotl32(uint32_t x, int d) {
  return (x << d) | (x >> (32 - d));
}

// Exact JAX threefry2x32 (20 rounds).
__device__ __forceinline__ void threefry2x32(uint32_t k0, uint32_t k1,
                                             uint32_t x0, uint32_t x1,
                                             uint32_t& o0, uint32_t& o1) {
  uint32_t ks2 = k0 ^ k1 ^ 0x1BD11BDAu;
  uint32_t v0 = x0 + k0, v1 = x1 + k1;
#define TF_R(r) { v0 += v1; v1 = rotl32(v1, r); v1 ^= v0; }
  TF_R(13) TF_R(15) TF_R(26) TF_R(6)
  v0 += k1;  v1 += ks2 + 1u;
  TF_R(17) TF_R(29) TF_R(16) TF_R(24)
  v0 += ks2; v1 += k0 + 2u;
  TF_R(13) TF_R(15) TF_R(26) TF_R(6)
  v0 += k0;  v1 += k1 + 3u;
  TF_R(17) TF_R(29) TF_R(16) TF_R(24)
  v0 += k1;  v1 += ks2 + 4u;
  TF_R(13) TF_R(15) TF_R(26) TF_R(6)
  v0 += ks2; v1 += k0 + 5u;
#undef TF_R
  o0 = v0; o1 = v1;
}

// Accurate sigmoid for the sampler (off critical path).
__device__ __forceinline__ float sigf(float x) { return 1.0f / (1.0f + expf(-x)); }

__device__ __forceinline__ uint64_t packht(float h, uint32_t tag) {
  return ((uint64_t)tag << 32) | (uint64_t)__float_as_uint(h);
}

__global__ __launch_bounds__(256, 1)
void arlstm_kernel(const float* __restrict__ W_ih, const float* __restrict__ W_hh,
                   const float* __restrict__ b_ih, const float* __restrict__ b_hh,
                   const float* __restrict__ W_out, const float* __restrict__ b_out,
                   float* __restrict__ out, uint64_t* __restrict__ ws) {
  // ws layout (u64 units):
  uint64_t* h_hist = ws;                                  // [512][256] tagged
  float*    obsbuf = (float*)(ws + 512 * 256);            // [2][512][2]
  uint32_t* p_prog = (uint32_t*)(obsbuf + 2 * 512 * 2);   // [4] sampler progress
  uint32_t* magic  = p_prog + 16;

  const int tid = threadIdx.x;
  const int blk = blockIdx.x;

  __shared__ __align__(16) float hstage[256];
  __shared__ float plds[4][64];
  __shared__ float obs_lds[2];
  __shared__ float lp_acc[512];
  __shared__ float ent_acc[512];
  __shared__ float red[256];

  if (blk == NBLK) {
    // ----------------------- init + sampler block -----------------------
    // h_hist slot 0 holds h_0 = 0 with tag 0.
    __hip_atomic_store(&h_hist[tid], 0ull, __ATOMIC_RELAXED, __HIP_MEMORY_SCOPE_AGENT);
    if (tid < 16)
      __hip_atomic_store(&p_prog[tid], 0u, __ATOMIC_RELAXED, __HIP_MEMORY_SCOPE_AGENT);
    out[(tid)       * NOUT] = 0.0f;   // samples column 0 = zeros
    out[(tid + 256) * NOUT] = 0.0f;
    lp_acc[tid] = 0.0f;  lp_acc[tid + 256] = 0.0f;
    ent_acc[tid] = 0.0f; ent_acc[tid + 256] = 0.0f;
    __threadfence();
    __syncthreads();
    if (tid == 0)
      __hip_atomic_store(magic, MAGIC_V, __ATOMIC_RELEASE, __HIP_MEMORY_SCOPE_AGENT);

    const int w    = tid >> 6;   // wave 0..3 handles steps s with (s-1)&3 == w
    const int lane = tid & 63;
    const float wo0 = W_out[lane * 4 + 0], wo1 = W_out[lane * 4 + 1];
    const float wo2 = W_out[lane * 4 + 2], wo3 = W_out[lane * 4 + 3];
    const float bo = b_out[0];

    for (int s = w + 1; s <= NSTEP; s += 4) {
      const int k = (s - 1) >> 9;
      const int t = (s - 1) & 511;
      uint64_t* src = h_hist + (uint64_t)(s & 511) * 256 + lane * 4;
      uint64_t v0, v1, v2, v3;
      for (;;) {
        v0 = __hip_atomic_load(src + 0, __ATOMIC_RELAXED, __HIP_MEMORY_SCOPE_AGENT);
        v1 = __hip_atomic_load(src + 1, __ATOMIC_RELAXED, __HIP_MEMORY_SCOPE_AGENT);
        v2 = __hip_atomic_load(src + 2, __ATOMIC_RELAXED, __HIP_MEMORY_SCOPE_AGENT);
        v3 = __hip_atomic_load(src + 3, __ATOMIC_RELAXED, __HIP_MEMORY_SCOPE_AGENT);
        int ok = ((uint32_t)(v0 >> 32) == (uint32_t)s) &
                 ((uint32_t)(v1 >> 32) == (uint32_t)s) &
                 ((uint32_t)(v2 >> 32) == (uint32_t)s) &
                 ((uint32_t)(v3 >> 32) == (uint32_t)s);
        if (__all(ok)) break;
      }
      float zp = fmaf(__uint_as_float((uint32_t)v0), wo0,
                 fmaf(__uint_as_float((uint32_t)v1), wo1,
                 fmaf(__uint_as_float((uint32_t)v2), wo2,
                      __uint_as_float((uint32_t)v3) * wo3)));
      zp += __shfl_xor(zp, 1);
      zp += __shfl_xor(zp, 2);
      zp += __shfl_xor(zp, 4);
      zp += __shfl_xor(zp, 8);
      zp += __shfl_xor(zp, 16);
      zp += __shfl_xor(zp, 32);
      const float p = sigf(zp + bo);

      // JAX partitionable threefry: key_k = tf((0,42),(0,k)); bits = xor of
      // tf(key_k,(0,t)); u = bitcast((bits>>9)|0x3f800000)-1; sample = u < p.
      uint32_t ka, kb, c1, c2;
      threefry2x32(0u, 42u, 0u, (uint32_t)k, ka, kb);
      threefry2x32(ka, kb, 0u, (uint32_t)t, c1, c2);
      const uint32_t bits = c1 ^ c2;
      const float u = __uint_as_float((bits >> 9) | 0x3f800000u) - 1.0f;
      const float smp = (u < p) ? 1.0f : 0.0f;

      if (lane == 0) {
        uint32_t* ob = (uint32_t*)(obsbuf + ((k + 1) & 1) * (512 * 2) + t * 2);
        __hip_atomic_store(&ob[0], __float_as_uint(smp), __ATOMIC_RELAXED, __HIP_MEMORY_SCOPE_AGENT);
        __hip_atomic_store(&ob[1], __float_as_uint(p),   __ATOMIC_RELAXED, __HIP_MEMORY_SCOPE_AGENT);
        __hip_atomic_store(&p_prog[w], (uint32_t)s, __ATOMIC_RELEASE, __HIP_MEMORY_SCOPE_AGENT);
        out[t * NOUT + (k + 1)] = smp;
        const float lg = logf(p), lg1 = log1pf(-p);
        lp_acc[t]  += (smp > 0.5f) ? lg : lg1;
        ent_acc[t] -= (p * lg + (1.0f - p) * lg1);
      }
    }
    __syncthreads();
    // final outputs: logprobs (centered), entropies (mean over 47)
    red[tid] = lp_acc[tid] + lp_acc[tid + 256];
    __syncthreads();
    for (int off = 128; off > 0; off >>= 1) {
      if (tid < off) red[tid] += red[tid + off];
      __syncthreads();
    }
    const float mean = red[0] * (1.0f / 512.0f);
    out[24576 + tid]        = lp_acc[tid]        - mean;
    out[24576 + 256 + tid]  = lp_acc[tid + 256]  - mean;
    out[25088 + tid]        = ent_acc[tid]       * (1.0f / 47.0f);
    out[25088 + 256 + tid]  = ent_acc[tid + 256] * (1.0f / 47.0f);
  } else {
    // --------------------------- LSTM worker ---------------------------
    const int part = tid >> 6;          // column quarter 0..3
    const int r    = tid & 63;          // local row (gate*16 + jloc)
    const int gate = r >> 4;
    const int jloc = r & 15;
    const int row  = gate * 256 + blk * 16 + jloc;

    float wreg[64];
#pragma unroll
    for (int c = 0; c < 64; ++c)
      wreg[c] = W_hh[row * 256 + part * 64 + c];

    // Per-lane epilogue constants (lanes 0..63: lane = gate*16 + j).
    float bb = 0.f, wx0 = 0.f, wx1 = 0.f, mconst = 0.f, ml = 0.f, ad = 0.f;
    if (tid < 64) {
      const int g4 = tid >> 4;
      const int rr = g4 * 256 + blk * 16 + (tid & 15);
      bb  = b_ih[rr] + b_hh[rr];
      wx0 = W_ih[rr * 2 + 0];
      wx1 = W_ih[rr * 2 + 1];
      mconst = (g4 == 2) ? (-2.0f * LOG2E) : (-LOG2E);  // act = ml*sig(sc*x)+ad
      ml     = (g4 == 2) ? 2.0f : 1.0f;
      ad     = (g4 == 2) ? -1.0f : 0.0f;
    }

    if (tid == 0) {
      while (__hip_atomic_load(magic, __ATOMIC_ACQUIRE, __HIP_MEMORY_SCOPE_AGENT) != MAGIC_V) {}
    }
    __syncthreads();

    float c_st = 0.0f;                      // cell state (lanes 0..15)
    const int jglob = blk * 16 + (tid & 15);

    for (int s = 1; s <= NSTEP; ++s) {
      const int k = (s - 1) >> 9;
      const int t = (s - 1) & 511;

      float samp = 0.0f, pv = 0.0f;
      if (tid == 255 && k > 0) {
        const uint32_t X = (uint32_t)((k - 1) * 512 + t + 1);
        while (__hip_atomic_load(&p_prog[t & 3], __ATOMIC_ACQUIRE, __HIP_MEMORY_SCOPE_AGENT) < X) {}
        uint32_t* ob = (uint32_t*)(obsbuf + (k & 1) * (512 * 2) + t * 2);
        samp = __uint_as_float(__hip_atomic_load(&ob[0], __ATOMIC_RELAXED, __HIP_MEMORY_SCOPE_AGENT));
        pv   = __uint_as_float(__hip_atomic_load(&ob[1], __ATOMIC_RELAXED, __HIP_MEMORY_SCOPE_AGENT));
      }

      {  // 2-deep pipelined spin on own self-tagged word of h_{s-1}
        uint64_t* src = h_hist + (uint64_t)((s - 1) & 511) * 256 + tid;
        const uint32_t want = (uint32_t)(s - 1);
        uint64_t v = __hip_atomic_load(src, __ATOMIC_RELAXED, __HIP_MEMORY_SCOPE_AGENT);
        if ((uint32_t)(v >> 32) != want) {
          uint64_t a = __hip_atomic_load(src, __ATOMIC_RELAXED, __HIP_MEMORY_SCOPE_AGENT);
          uint64_t b = __hip_atomic_load(src, __ATOMIC_RELAXED, __HIP_MEMORY_SCOPE_AGENT);
          for (;;) {
            if ((uint32_t)(a >> 32) == want) { v = a; break; }
            a = __hip_atomic_load(src, __ATOMIC_RELAXED, __HIP_MEMORY_SCOPE_AGENT);
            if ((uint32_t)(b >> 32) == want) { v = b; break; }
            b = __hip_atomic_load(src, __ATOMIC_RELAXED, __HIP_MEMORY_SCOPE_AGENT);
          }
        }
        hstage[tid] = __uint_as_float((uint32_t)v);
      }
      if (tid == 255) { obs_lds[0] = samp; obs_lds[1] = pv; }
      __syncthreads();

      float a0 = 0.f, a1 = 0.f, a2 = 0.f, a3 = 0.f;
      const float4* hs4 = (const float4*)(hstage + part * 64);
#pragma unroll
      for (int i = 0; i < 16; ++i) {
        const float4 hv = hs4[i];
        a0 = fmaf(wreg[4 * i + 0], hv.x, a0);
        a1 = fmaf(wreg[4 * i + 1], hv.y, a1);
        a2 = fmaf(wreg[4 * i + 2], hv.z, a2);
        a3 = fmaf(wreg[4 * i + 3], hv.w, a3);
      }
      plds[part][r] = (a0 + a1) + (a2 + a3);
      __syncthreads();

      if (tid < 64) {
        // One gate per lane: gv = full gate pre-activation.
        const float sx = obs_lds[0], px = obs_lds[1];
        const float base = wx0 * sx + wx1 * px + bb;
        const float gv = ((plds[0][tid] + plds[1][tid]) +
                          (plds[2][tid] + plds[3][tid])) + base;
        // act = sig(gv) for gates i,f,o; tanh(gv) = 2*sig(2gv)-1 for gate g.
        const float e   = __builtin_amdgcn_exp2f(gv * mconst);
        const float y   = __builtin_amdgcn_rcpf(1.0f + e);
        const float act = __builtin_fmaf(ml, y, ad);
        const int j = tid & 15;
        const float a_f = __shfl(act, j + 16, 64);
        const float a_g = __shfl(act, j + 32, 64);
        const float a_o = __shfl(act, j + 48, 64);
        if (tid < 16) {
          const float t1 = a_f * c_st;
          const float t2 = act * a_g;     // act = sig(i) on lanes 0..15
          c_st = t1 + t2;
          const float ec = __builtin_amdgcn_exp2f(c_st * (-2.0f * LOG2E));
          const float yc = __builtin_amdgcn_rcpf(1.0f + ec);
          const float th = __builtin_fmaf(2.0f, yc, -1.0f);
          const float hnew = a_o * th;
          __hip_atomic_store(&h_hist[(uint64_t)(s & 511) * 256 + jglob],
                             packht(hnew, (uint32_t)s),
                             __ATOMIC_RELAXED, __HIP_MEMORY_SCOPE_AGENT);
        }
      }
    }
  }
}

extern "C" void kernel_launch(void* const* d_in, const int* in_sizes, int n_in,
                              void* d_out, int out_size, void* d_ws, size_t ws_size,
                              hipStream_t stream) {
  const float* W_ih  = (const float*)d_in[0];
  const float* W_hh  = (const float*)d_in[1];
  const float* b_ih  = (const float*)d_in[2];
  const float* b_hh  = (const float*)d_in[3];
  const float* W_out = (const float*)d_in[4];
  const float* b_out = (const float*)d_in[5];
  float* out = (float*)d_out;
  uint64_t* ws = (uint64_t*)d_ws;

  arlstm_kernel<<<dim3(NBLK + 1), dim3(256), 0, stream>>>(
      W_ih, W_hh, b_ih, b_hh, W_out, b_out, out, ws);
}